// Round 5
// baseline (460.042 us; speedup 1.0000x reference)
//
#include <hip/hip_runtime.h>
#include <hip/hip_bf16.h>

// GAT on two 512-node cliques + bipartite cross edges, 5 GATConv layers.
// Dense-in-disguise edges: "inside" = clique within each set (+self),
// "cross" = full bipartite to opposite set (+self).
//
// SINGLE PERSISTENT KERNEL: 256 blocks (1/CU, co-resident) x 512 threads.
// Phases: prep -> 4x fused GAT layer (separable softmax via rank+scan,
// validated round 4 absmax=0) -> mm2 -> att2. Grid-wide sync via a
// monotonic device-scope atomic barrier (counter zeroed by init kernel).
// All internal compute f32; input/output dtype runtime-detected f32/bf16.

typedef __hip_bfloat16 bf16;

__device__ __forceinline__ float b2f(bf16 x) { return __bfloat162float(x); }

__device__ __forceinline__ int detect_bf16(const void* desc1) {
  const unsigned* u = (const unsigned*)desc1;
  int hits = 0;
#pragma unroll 8
  for (int i = 0; i < 256; ++i) {
    unsigned e = (u[i] >> 7) & 0xFFu;
    hits += (e >= 100u && e <= 140u) ? 1 : 0;
  }
  return hits >= 200 ? 1 : 0;
}

__device__ __forceinline__ float load_in(const void* p, int i, int bf) {
  return bf ? b2f(((const bf16*)p)[i]) : ((const float*)p)[i];
}

// Monotonic grid barrier: block arrives (+1), spins until 256*phase arrivals.
// Device-scope atomics are cross-XCD coherent; __threadfence() = agent fence.
__device__ __forceinline__ void grid_barrier(unsigned* cnt, unsigned phase) {
  __syncthreads();
  if (threadIdx.x == 0) {
    __threadfence();
    atomicAdd(cnt, 1u);
    const unsigned target = 256u * phase;
    while (atomicAdd(cnt, 0u) < target) { __builtin_amdgcn_s_sleep(2); }
  }
  __syncthreads();
  __threadfence();
}

__global__ void init_kernel(unsigned* cnt) {
  if (threadIdx.x == 0) *cnt = 0u;
}

// ---------------------------------------------------------- layer phase ----
// Block (S,hd): sources = set S; dst = S (inside) or 1-S (cross).
// Separable softmax: exp(lrelu(s_j+d_i)) = exp(s_j)exp(d_i) if s_j >= -d_i,
// else exp(.2 s_j)exp(.2 d_i).  Rank by compare-all, float4 scan, per-dst
// binary search + O(1) combine.  (Validated round 4: absmax 0.)
__device__ __forceinline__ void layer_phase(
    int cross, int hd, int S, int tid,
    const float* __restrict__ xt_in, float* __restrict__ xt_out,
    const float* __restrict__ Wf, const float* __restrict__ vecs,
    float* sm) {
  float*  ss      = sm;                  // 512
  float*  sortedS = sm + 512;            // 512
  float*  sortedH = sm + 1024;           // 512
  float4* scanA   = (float4*)(sm + 1536);  // 512 float4
  float4* scanB   = (float4*)(sm + 3584);  // 512 float4

  const int D = cross ? (1 - S) : S;
  const float a_src = vecs[hd], a_dst = vecs[128 + hd], bias = vecs[256 + hd];

  // Phase A: h column for this head.
  float accSa = 0.f, accSb = 0.f, accDa = 0.f, accDb = 0.f;
#pragma unroll 8
  for (int k = 0; k < 128; k += 2) {
    float w0 = Wf[k * 128 + hd];
    float w1 = Wf[(k + 1) * 128 + hd];
    accSa = fmaf(xt_in[k * 1024 + S * 512 + tid],       w0, accSa);
    accSb = fmaf(xt_in[(k + 1) * 1024 + S * 512 + tid], w1, accSb);
    if (cross) {
      accDa = fmaf(xt_in[k * 1024 + D * 512 + tid],       w0, accDa);
      accDb = fmaf(xt_in[(k + 1) * 1024 + D * 512 + tid], w1, accDb);
    }
  }
  const float h_src = accSa + accSb;
  const float h_dst = cross ? (accDa + accDb) : h_src;
  const float s_own = h_src * a_src;
  const float d_own = h_dst * a_dst;
  ss[tid] = s_own;
  __syncthreads();

  // Phase B: rank by compare-all (stable via index tie-break), scatter.
  {
    int r = 0;
#pragma unroll 8
    for (int j = 0; j < 512; ++j) {
      float sj = ss[j];
      r += (sj < s_own || (sj == s_own && j < tid)) ? 1 : 0;
    }
    sortedS[r] = s_own;
    sortedH[r] = h_src;
  }
  __syncthreads();

  // Phase C: exp + pack (E2, E2*h, rev(E1), rev(E1*h)).
  {
    float sv = sortedS[tid];
    float hv = sortedH[tid];
    float e1 = __expf(sv), e2 = __expf(0.2f * sv);
    scanA[tid].x = e2;
    scanA[tid].y = e2 * hv;
    scanA[511 - tid].z = e1;
    scanA[511 - tid].w = e1 * hv;
  }
  __syncthreads();

  // Phase D: inclusive Hillis-Steele scan over 512 float4s (9 steps).
  float4* srcb = scanA;
  float4* dstb = scanB;
  for (int d = 1; d < 512; d <<= 1) {
    float4 v = srcb[tid];
    if (tid >= d) {
      float4 u = srcb[tid - d];
      v.x += u.x; v.y += u.y; v.z += u.z; v.w += u.w;
    }
    dstb[tid] = v;
    __syncthreads();
    float4* t = srcb; srcb = dstb; dstb = t;
  }
  const float4* SC = srcb;

  // Phase E: this thread's destination: binary search + O(1) combine.
  {
    const float theta = -d_own;
    int k = 0;
#pragma unroll
    for (int s = 512; s > 0; s >>= 1) {
      int nk = k + s;
      if (nk <= 512 && sortedS[nk - 1] < theta) k = nk;
    }
    float F1 = __expf(d_own), F2 = __expf(0.2f * d_own);
    float P2 = 0.f, P2h = 0.f, S1 = 0.f, S1h = 0.f;
    if (k > 0)   { float4 t4 = SC[k - 1];   P2 = t4.x; P2h = t4.y; }
    if (k < 512) { float4 t4 = SC[511 - k]; S1 = t4.z; S1h = t4.w; }
    float den = F1 * S1 + F2 * P2;
    float num = F1 * S1h + F2 * P2h;
    if (cross) {  // self-loop
      float t = h_dst * a_src + d_own;
      float p = __expf(fmaxf(t, 0.2f * t));
      den += p;
      num = fmaf(p, h_dst, num);
    }
    float o = num / (den + 1e-16f) + bias;
    o = (o > 0.f) ? o : expm1f(o);  // ELU
    xt_out[hd * 1024 + D * 512 + tid] = o;
  }
  __syncthreads();  // protect LDS before next phase reuses it
}

// ------------------------------------------------------------ mega kernel ----
__global__ __launch_bounds__(512) void mega_kernel(
    const void* __restrict__ desc1, const void* __restrict__ desc2,
    const void* __restrict__ W1,   const void* __restrict__ as1,
    const void* __restrict__ ad1,  const void* __restrict__ b1,
    const void* __restrict__ W2,   const void* __restrict__ as2,
    const void* __restrict__ ad2,  const void* __restrict__ b2_,
    float* __restrict__ xtA, float* __restrict__ xtB,
    float* __restrict__ h2,  float* __restrict__ W1f,
    float* __restrict__ W2f, float* __restrict__ vecs,
    float* __restrict__ s2,  float* __restrict__ d2,
    unsigned* __restrict__ cnt, void* __restrict__ out) {
  __shared__ float sm[5632];  // 22.5 KB, reused across phases
  const int tid = threadIdx.x;
  const int b   = blockIdx.x;
  const int hd  = b & 127;
  const int S   = b >> 7;
  const int bf  = detect_bf16(desc1);

  // ---- P0: prep (convert inputs to f32, transpose x) ----
  {
    const int total = 131072 + 16384 + 16384 + 6 * 128;
    for (int idx = b * 512 + tid; idx < total; idx += 131072) {
      if (idx < 131072) {
        int n = idx & 1023, c = idx >> 10;
        float v = (n < 512) ? load_in(desc1, n * 128 + c, bf)
                            : load_in(desc2, (n - 512) * 128 + c, bf);
        xtA[idx] = v;  // xt[c*1024 + n]
      } else if (idx < 147456) {
        W1f[idx - 131072] = load_in(W1, idx - 131072, bf);
      } else if (idx < 163840) {
        W2f[idx - 147456] = load_in(W2, idx - 147456, bf);
      } else {
        int i = idx - 163840, o = i & 127;
        float v;
        if      (i < 128) v = load_in(as1, o, bf);
        else if (i < 256) v = load_in(ad1, o, bf);
        else if (i < 384) v = load_in(b1, o, bf);
        else if (i < 512) v = load_in(as2, o, bf);
        else if (i < 640) v = load_in(ad2, o, bf);
        else              v = load_in(b2_, o, bf);
        vecs[i] = v;
      }
    }
  }
  grid_barrier(cnt, 1);

  // ---- P1..P4: four GAT layers ----
  layer_phase(0, hd, S, tid, xtA, xtB, W1f, vecs, sm);
  grid_barrier(cnt, 2);
  layer_phase(1, hd, S, tid, xtB, xtA, W1f, vecs, sm);
  grid_barrier(cnt, 3);
  layer_phase(0, hd, S, tid, xtA, xtB, W1f, vecs, sm);
  grid_barrier(cnt, 4);
  layer_phase(1, hd, S, tid, xtB, xtA, W1f, vecs, sm);
  grid_barrier(cnt, 5);

  // ---- P5: mm2 (h2 = x@W2, s2/d2 row dots).  4 rows x 128 cols/block ----
  {
    float* rs = sm;        // 512
    float* rd = sm + 512;  // 512
    const int row = b * 4 + (tid >> 7);
    const int c = tid & 127;
    float acca = 0.f, accb = 0.f;
#pragma unroll 8
    for (int k = 0; k < 128; k += 2) {
      acca = fmaf(xtA[k * 1024 + row], W2f[k * 128 + c], acca);
      accb = fmaf(xtA[(k + 1) * 1024 + row], W2f[(k + 1) * 128 + c], accb);
    }
    float acc = acca + accb;
    h2[row * 128 + c] = acc;
    rs[tid] = acc * vecs[384 + c];  // a_src2
    rd[tid] = acc * vecs[512 + c];  // a_dst2
    __syncthreads();
    for (int off = 64; off > 0; off >>= 1) {
      if ((tid & 127) < off) { rs[tid] += rs[tid + off]; rd[tid] += rd[tid + off]; }
      __syncthreads();
    }
    if ((tid & 127) == 0) {
      s2[row] = rs[tid];
      d2[row] = rd[tid];
    }
    __syncthreads();
  }
  grid_barrier(cnt, 6);

  // ---- P6: final attention (heads=1, ch=128), direct weighted row-sum ----
  {
    float* pL = sm;  // [4][512]
    const int dstBase = b * 4;
    const int srcBase = (dstBase < 512) ? 512 : 0;  // cross edges

    for (int e = tid; e < 2048; e += 512) {
      int ld = e >> 9, j = e & 511;
      float t = s2[srcBase + j] + d2[dstBase + ld];
      pL[ld * 512 + j] = __expf(fmaxf(t, 0.2f * t));
    }
    __syncthreads();

    const int ld = tid >> 7, c = tid & 127;
    const int i = dstBase + ld;
    float acc = 0.f, den = 0.f;
    const float* hrow = h2 + srcBase * 128 + c;
#pragma unroll 4
    for (int j = 0; j < 512; ++j) {
      float p = pL[ld * 512 + j];
      den += p;
      acc = fmaf(p, hrow[j * 128], acc);
    }
    float ts = s2[i] + d2[i];
    float ps = __expf(fmaxf(ts, 0.2f * ts));  // self-loop
    den += ps;
    acc = fmaf(ps, h2[i * 128 + c], acc);
    float o = acc / (den + 1e-16f) + vecs[640 + c];
    if (bf) ((bf16*)out)[i * 128 + c] = __float2bfloat16(o);
    else    ((float*)out)[i * 128 + c] = o;
  }
}

// ------------------------------------------------------------- launcher ----
extern "C" void kernel_launch(void* const* d_in, const int* in_sizes, int n_in,
                              void* d_out, int out_size, void* d_ws, size_t ws_size,
                              hipStream_t stream) {
  (void)in_sizes; (void)n_in; (void)out_size; (void)ws_size;
  float* ws   = (float*)d_ws;
  float* xtA  = ws;            // 131072
  float* xtB  = ws + 131072;   // 131072
  float* h2   = ws + 262144;   // 131072
  float* W1f  = ws + 393216;   // 16384
  float* W2f  = ws + 409600;   // 16384
  float* vecs = ws + 425984;   // 768
  float* s2   = ws + 426752;   // 1024
  float* d2   = ws + 427776;   // 1024
  unsigned* cnt = (unsigned*)(ws + 428800);

  init_kernel<<<1, 64, 0, stream>>>(cnt);
  mega_kernel<<<256, 512, 0, stream>>>(
      d_in[0], d_in[1], d_in[2], d_in[3], d_in[4], d_in[5],
      d_in[6], d_in[7], d_in[8], d_in[9],
      xtA, xtB, h2, W1f, W2f, vecs, s2, d2, cnt, d_out);
}

// Round 6
// 225.838 us; speedup vs baseline: 2.0370x; 2.0370x over previous
//
#include <hip/hip_runtime.h>
#include <hip/hip_bf16.h>

// GAT on two 512-node cliques + bipartite cross edges, 5 GATConv layers.
// Dense-in-disguise edges: "inside" = clique within each set (+self),
// "cross" = full bipartite to opposite set (+self).
//
// R6: direct dense layers (math validated R3/R4, absmax 0), engineered to
// the VALU floor: fused matmul+attention per layer, float4 LDS broadcasts
// (kills the LDS-pipe bottleneck that capped R3/R4 at ~20us/layer), 4
// independent accumulator chains. No grid barriers (R5 spin barrier cost
// ~340us — reverted). All internal f32; input/output dtype runtime-detected.

typedef __hip_bfloat16 bf16;

__device__ __forceinline__ float b2f(bf16 x) { return __bfloat162float(x); }

__device__ __forceinline__ int detect_bf16(const void* desc1) {
  const unsigned* u = (const unsigned*)desc1;
  int hits = 0;
#pragma unroll 8
  for (int i = 0; i < 256; ++i) {
    unsigned e = (u[i] >> 7) & 0xFFu;
    hits += (e >= 100u && e <= 140u) ? 1 : 0;
  }
  return hits >= 200 ? 1 : 0;
}

__device__ __forceinline__ float load_in(const void* p, int i, int bf) {
  return bf ? b2f(((const bf16*)p)[i]) : ((const float*)p)[i];
}

// ---------------------------------------------------------------- prep ----
__global__ __launch_bounds__(256) void prep_kernel(
    const void* __restrict__ desc1, const void* __restrict__ desc2,
    const void* __restrict__ W1,   const void* __restrict__ as1,
    const void* __restrict__ ad1,  const void* __restrict__ b1,
    const void* __restrict__ W2,   const void* __restrict__ as2,
    const void* __restrict__ ad2,  const void* __restrict__ b2,
    float* __restrict__ xt, float* __restrict__ W1f, float* __restrict__ W2f,
    float* __restrict__ vecs, int* __restrict__ flag) {
  const int bf = detect_bf16(desc1);
  if (blockIdx.x == 0 && threadIdx.x == 0) *flag = bf;
  const int total = 131072 + 16384 + 16384 + 6 * 128;
  for (int idx = blockIdx.x * blockDim.x + threadIdx.x; idx < total;
       idx += gridDim.x * blockDim.x) {
    if (idx < 131072) {
      int n = idx & 1023, c = idx >> 10;
      float v = (n < 512) ? load_in(desc1, n * 128 + c, bf)
                          : load_in(desc2, (n - 512) * 128 + c, bf);
      xt[idx] = v;  // xt[c*1024 + n]
    } else if (idx < 147456) {
      W1f[idx - 131072] = load_in(W1, idx - 131072, bf);
    } else if (idx < 163840) {
      W2f[idx - 147456] = load_in(W2, idx - 147456, bf);
    } else {
      int i = idx - 163840, o = i & 127;
      float v;
      if      (i < 128) v = load_in(as1, o, bf);
      else if (i < 256) v = load_in(ad1, o, bf);
      else if (i < 384) v = load_in(b1, o, bf);
      else if (i < 512) v = load_in(as2, o, bf);
      else if (i < 640) v = load_in(ad2, o, bf);
      else              v = load_in(b2, o, bf);
      vecs[i] = v;
    }
  }
}

// ------------------------------------------------------- fused GAT layer ----
// grid 256 = (S<<7)|hd, 512 threads; 1 block/CU.  Block (hd,S): sources =
// set S; dst = S (inside) or 1-S (cross).  Phase A: h column (own matmul).
// Phase B: direct 512-term softmax, float4 LDS broadcasts, 4 acc chains.
template <int CROSS>
__global__ __launch_bounds__(512) void layer_kernel(
    const float* __restrict__ xt_in, float* __restrict__ xt_out,
    const float* __restrict__ Wf, const float* __restrict__ vecs) {
  __shared__ __align__(16) float ssA[512];
  __shared__ __align__(16) float hhA[512];

  const int tid = threadIdx.x;
  const int hd  = blockIdx.x & 127;
  const int S   = blockIdx.x >> 7;
  const int D   = CROSS ? (1 - S) : S;
  const float a_src = vecs[hd], a_dst = vecs[128 + hd], bias = vecs[256 + hd];

  // Phase A: h column for this head (src set; dst set too if cross).
  float accSa = 0.f, accSb = 0.f, accDa = 0.f, accDb = 0.f;
#pragma unroll 8
  for (int k = 0; k < 128; k += 2) {
    float w0 = Wf[k * 128 + hd];
    float w1 = Wf[(k + 1) * 128 + hd];
    accSa = fmaf(xt_in[k * 1024 + S * 512 + tid],       w0, accSa);
    accSb = fmaf(xt_in[(k + 1) * 1024 + S * 512 + tid], w1, accSb);
    if (CROSS) {
      accDa = fmaf(xt_in[k * 1024 + D * 512 + tid],       w0, accDa);
      accDb = fmaf(xt_in[(k + 1) * 1024 + D * 512 + tid], w1, accDb);
    }
  }
  const float h_src = accSa + accSb;
  const float h_dst = CROSS ? (accDa + accDb) : h_src;
  const float d_own = h_dst * a_dst;     // dst score of node D*512+tid
  ssA[tid] = h_src * a_src;              // source scores
  hhA[tid] = h_src;
  __syncthreads();

  // Phase B: direct reduction, 4 src per float4 read, 4 acc chains.
  float den0 = 0.f, den1 = 0.f, den2 = 0.f, den3 = 0.f;
  float num0 = 0.f, num1 = 0.f, num2 = 0.f, num3 = 0.f;
#pragma unroll 4
  for (int j = 0; j < 512; j += 4) {
    float4 sv = *(const float4*)(ssA + j);
    float4 hv = *(const float4*)(hhA + j);
    float t0 = sv.x + d_own, t1 = sv.y + d_own;
    float t2 = sv.z + d_own, t3 = sv.w + d_own;
    float p0 = __expf(fmaxf(t0, 0.2f * t0));
    float p1 = __expf(fmaxf(t1, 0.2f * t1));
    float p2 = __expf(fmaxf(t2, 0.2f * t2));
    float p3 = __expf(fmaxf(t3, 0.2f * t3));
    den0 += p0; num0 = fmaf(p0, hv.x, num0);
    den1 += p1; num1 = fmaf(p1, hv.y, num1);
    den2 += p2; num2 = fmaf(p2, hv.z, num2);
    den3 += p3; num3 = fmaf(p3, hv.w, num3);
  }
  float den = (den0 + den1) + (den2 + den3);
  float num = (num0 + num1) + (num2 + num3);
  if (CROSS) {  // self-loop: dst node's own source score
    float t = h_dst * a_src + d_own;
    float p = __expf(fmaxf(t, 0.2f * t));
    den += p;
    num = fmaf(p, h_dst, num);
  }
  float o = num / (den + 1e-16f) + bias;
  o = (o > 0.f) ? o : expm1f(o);  // ELU
  xt_out[hd * 1024 + D * 512 + tid] = o;
}

// ----------------------------------------------------- final layer: mm2 ----
// grid 512 x 256: 2 rows x 128 cols per block.  h2 = x@W2, s2/d2 row dots.
__global__ __launch_bounds__(256) void mm2_kernel(
    const float* __restrict__ xt_in, const float* __restrict__ W2f,
    const float* __restrict__ vecs, float* __restrict__ h2,
    float* __restrict__ s2, float* __restrict__ d2) {
  __shared__ float rs[256], rd[256];
  const int tid = threadIdx.x;
  const int row = blockIdx.x * 2 + (tid >> 7);
  const int c = tid & 127;
  float acca = 0.f, accb = 0.f;
#pragma unroll 8
  for (int k = 0; k < 128; k += 2) {
    acca = fmaf(xt_in[k * 1024 + row], W2f[k * 128 + c], acca);
    accb = fmaf(xt_in[(k + 1) * 1024 + row], W2f[(k + 1) * 128 + c], accb);
  }
  float acc = acca + accb;
  h2[row * 128 + c] = acc;
  rs[tid] = acc * vecs[384 + c];  // a_src2
  rd[tid] = acc * vecs[512 + c];  // a_dst2
  __syncthreads();
  for (int off = 64; off > 0; off >>= 1) {
    if ((tid & 127) < off) { rs[tid] += rs[tid + off]; rd[tid] += rd[tid + off]; }
    __syncthreads();
  }
  if ((tid & 127) == 0) {
    s2[row] = rs[tid];
    d2[row] = rd[tid];
  }
}

// ---------------------------------------------------- final layer: attn ----
// Final conv: heads=1, ch=128, cross edges + self, no ELU, +b2.
// grid 256 x 256: 4 dst per block; thread (g,c) handles dsts dstBase+2g,+2g+1
// for channel c.  p staged in LDS as pT[j] = float4 over the 4 dsts; inner
// loop: 1 coalesced h2 load + 1 float2 LDS broadcast serves 2 terms.
__global__ __launch_bounds__(256) void att2_kernel(
    const float* __restrict__ h2, const float* __restrict__ s2,
    const float* __restrict__ d2, const float* __restrict__ vecs,
    void* __restrict__ out, const int* __restrict__ flag) {
  __shared__ __align__(16) float pT[512 * 4];  // pT[j*4 + ld]
  const int tid = threadIdx.x;
  const int dstBase = blockIdx.x * 4;
  const int srcBase = (dstBase < 512) ? 512 : 0;  // cross edges

  for (int e = tid; e < 2048; e += 256) {
    int j = e >> 2, ld = e & 3;
    float t = s2[srcBase + j] + d2[dstBase + ld];
    pT[e] = __expf(fmaxf(t, 0.2f * t));
  }
  __syncthreads();

  const int c = tid & 127;
  const int g = tid >> 7;            // 0 or 1 -> dst pair
  const int i0 = dstBase + 2 * g, i1 = i0 + 1;
  float den0 = 0.f, num0 = 0.f, den1 = 0.f, num1 = 0.f;
  const float* hrow = h2 + srcBase * 128 + c;
#pragma unroll 4
  for (int j = 0; j < 512; ++j) {
    float2 pv = *(const float2*)(pT + j * 4 + 2 * g);
    float hval = hrow[j * 128];
    den0 += pv.x; num0 = fmaf(pv.x, hval, num0);
    den1 += pv.y; num1 = fmaf(pv.y, hval, num1);
  }
  // self-loops
  float ts0 = s2[i0] + d2[i0];
  float ps0 = __expf(fmaxf(ts0, 0.2f * ts0));
  den0 += ps0; num0 = fmaf(ps0, h2[i0 * 128 + c], num0);
  float ts1 = s2[i1] + d2[i1];
  float ps1 = __expf(fmaxf(ts1, 0.2f * ts1));
  den1 += ps1; num1 = fmaf(ps1, h2[i1 * 128 + c], num1);

  float o0 = num0 / (den0 + 1e-16f) + vecs[640 + c];
  float o1 = num1 / (den1 + 1e-16f) + vecs[640 + c];
  if (*flag) {
    ((bf16*)out)[i0 * 128 + c] = __float2bfloat16(o0);
    ((bf16*)out)[i1 * 128 + c] = __float2bfloat16(o1);
  } else {
    ((float*)out)[i0 * 128 + c] = o0;
    ((float*)out)[i1 * 128 + c] = o1;
  }
}

// ------------------------------------------------------------- launcher ----
extern "C" void kernel_launch(void* const* d_in, const int* in_sizes, int n_in,
                              void* d_out, int out_size, void* d_ws, size_t ws_size,
                              hipStream_t stream) {
  (void)in_sizes; (void)n_in; (void)out_size; (void)ws_size;
  float* ws   = (float*)d_ws;
  float* xtA  = ws;            // 131072
  float* xtB  = ws + 131072;   // 131072
  float* h2   = ws + 262144;   // 131072
  float* W1f  = ws + 393216;   // 16384
  float* W2f  = ws + 409600;   // 16384
  float* vecs = ws + 425984;   // 768
  float* s2   = ws + 426752;   // 1024
  float* d2   = ws + 427776;   // 1024
  int*   flag = (int*)(ws + 428800);

  prep_kernel<<<64, 256, 0, stream>>>(d_in[0], d_in[1], d_in[2], d_in[3],
                                      d_in[4], d_in[5], d_in[6], d_in[7],
                                      d_in[8], d_in[9], xtA, W1f, W2f, vecs, flag);
  layer_kernel<0><<<256, 512, 0, stream>>>(xtA, xtB, W1f, vecs);  // L1 inside
  layer_kernel<1><<<256, 512, 0, stream>>>(xtB, xtA, W1f, vecs);  // L2 cross
  layer_kernel<0><<<256, 512, 0, stream>>>(xtA, xtB, W1f, vecs);  // L3 inside
  layer_kernel<1><<<256, 512, 0, stream>>>(xtB, xtA, W1f, vecs);  // L4 cross
  mm2_kernel<<<512, 256, 0, stream>>>(xtA, W2f, vecs, h2, s2, d2);
  att2_kernel<<<256, 256, 0, stream>>>(h2, s2, d2, vecs, d_out, flag);
}